// Round 3
// baseline (421.229 us; speedup 1.0000x reference)
//
#include <hip/hip_runtime.h>

// Reference is the identity on x (float32): a pure 256 MiB D2D copy.
// Total HBM traffic 1.074 GB -> roofline ~171 us at 6.3 TB/s achievable.
//
// R1 post-mortem: hipMemcpyAsync D2D crashed the container (graph capture
// cannot record the SDMA blit path). Compute-kernel copy it is.
// R2 post-mortem: __builtin_nontemporal_* rejects HIP_vector_type<float,4>
// (a struct); it requires a NATIVE clang vector. Use ext_vector_type(4).
//
// R3: same experiment as R2, compiling this time --
//  - grid-stride, grid capped at 2048 blocks (256 CU x 8 blocks/CU).
//  - nontemporal native-float4 load/store: zero-reuse streaming data.
// Prediction: copy dispatch stays < 164 us (at roofline); harness poison
// fills (2 x ~166 us) keep dur_us ~413 us. A >10 us drop falsifies the
// fixed-floor hypothesis.

typedef float vfloat4 __attribute__((ext_vector_type(4)));

__global__ __launch_bounds__(256) void identity_copy_nt(
    const vfloat4* __restrict__ in, vfloat4* __restrict__ out, long long n4) {
    long long stride = (long long)gridDim.x * blockDim.x;
    for (long long i = (long long)blockIdx.x * blockDim.x + threadIdx.x;
         i < n4; i += stride) {
        vfloat4 v = __builtin_nontemporal_load(&in[i]);
        __builtin_nontemporal_store(v, &out[i]);
    }
}

extern "C" void kernel_launch(void* const* d_in, const int* in_sizes, int n_in,
                              void* d_out, int out_size, void* d_ws, size_t ws_size,
                              hipStream_t stream) {
    const float* x = (const float*)d_in[0];
    float* out = (float*)d_out;

    long long n = (long long)in_sizes[0];   // 64 * 2^20 = 67,108,864 floats
    long long n4 = n / 4;                   // 16,777,216 float4s (n % 4 == 0)

    const int block = 256;
    // Cap grid at 2048 blocks (256 CUs x 8 blocks/CU), grid-stride the rest.
    long long grid_needed = (n4 + block - 1) / block;
    int grid = (int)(grid_needed < 2048 ? grid_needed : 2048);

    identity_copy_nt<<<dim3(grid), dim3(block), 0, stream>>>(
        (const vfloat4*)x, (vfloat4*)out, n4);
}

// Round 4
// 411.573 us; speedup vs baseline: 1.0235x; 1.0235x over previous
//
#include <hip/hip_runtime.h>

// Reference is the identity on x (float32): a pure 268 MB D2D copy
// (268 MB read + 268 MB write = 537 MB HBM traffic -> ~85 us roofline
// at 6.3 TB/s achievable).
//
// Session decomposition (R0-R3): dur_us ~= 332 us of harness poison fills
// (2 x 166 us, 1 GiB each at ~81% HBM peak -- uncontrollable) + the copy.
//   R0 plain float4 copy:            copy ~= 81 us  (at/under roofline)
//   R3 nontemporal + grid-stride:    copy ~= 89 us  (NT hint defeats L3
//     residency of the 268 MB input; 256 MiB Infinity Cache nearly fits it)
// => revert to the R0 kernel, the verified best (412.3/413.1 us wall).

__global__ __launch_bounds__(256) void identity_copy_f4(
    const float4* __restrict__ in, float4* __restrict__ out, long long n4) {
    long long i = (long long)blockIdx.x * blockDim.x + threadIdx.x;
    if (i < n4) {
        out[i] = in[i];
    }
}

extern "C" void kernel_launch(void* const* d_in, const int* in_sizes, int n_in,
                              void* d_out, int out_size, void* d_ws, size_t ws_size,
                              hipStream_t stream) {
    const float* x = (const float*)d_in[0];
    float* out = (float*)d_out;

    long long n = (long long)in_sizes[0];   // 64 * 2^20 = 67,108,864 floats
    long long n4 = n / 4;                   // 16,777,216 float4s (n % 4 == 0)

    const int block = 256;
    long long grid = (n4 + block - 1) / block;

    identity_copy_f4<<<dim3((unsigned)grid), dim3(block), 0, stream>>>(
        (const float4*)x, (float4*)out, n4);
}